// Round 1
// baseline (234.298 us; speedup 1.0000x reference)
//
#include <hip/hip_runtime.h>
#include <stdint.h>

// Problem dims (fixed by the reference's setup_inputs)
#define B    8
#define W    128
#define Hdim 128
#define C    80
#define M    100
#define NPIX (W * Hdim)   // 16384
#define NT   128          // n-cells per block (== blockDim.x)

#define ALPHA_F 0.25f
#define EPS_F   1e-8f

// Order-preserving float -> uint32 map (total order; no NaNs expected here).
__device__ __forceinline__ uint32_t fkey(float f) {
    uint32_t u = __float_as_uint(f);
    return (u & 0x80000000u) ? ~u : (u | 0x80000000u);
}

// ---------------------------------------------------------------------------
// Kernel 1: per-(b,m) init: min-key = +inf, cid = argmax of one-hot cls_true
// ---------------------------------------------------------------------------
__global__ void init_kernel(const float* __restrict__ cls_true,
                            unsigned long long* __restrict__ keys,
                            int* __restrict__ cids) {
    int i = blockIdx.x * blockDim.x + threadIdx.x;
    if (i >= B * M) return;
    keys[i] = 0xFFFFFFFFFFFFFFFFull;
    const float* ct = cls_true + (size_t)i * C;
    int best = 0;
    float bv = ct[0];
    for (int c = 1; c < C; ++c) {
        float v = ct[c];
        if (v > bv) { bv = v; best = c; }   // strict > => first max index
    }
    cids[i] = best;
}

// ---------------------------------------------------------------------------
// Kernel 2: main matcher. Block = (tile of NT cells, batch b).
// Stages focal class costs D[c][n] + all (loc_true, cid) in LDS, then loops m.
// ---------------------------------------------------------------------------
__global__ __launch_bounds__(NT) void match_kernel(
    const float* __restrict__ cls_pred,   // (B, NPIX, C)
    const float* __restrict__ loc_pred,   // (B, NPIX, 4)
    const float* __restrict__ loc_true,   // (B, M, 4)
    const int*   __restrict__ cids,       // (B*M)
    unsigned long long* __restrict__ keys) // (B*M)
{
#pragma clang fp contract(off)
    __shared__ float D[C][NT + 1];   // +1 pad: conflict-free column reads
    __shared__ float lt[M][4];
    __shared__ int   lcid[M];

    const int b   = blockIdx.y;
    const int n0  = blockIdx.x * NT;
    const int tid = threadIdx.x;

    // ---- stage focal class-cost tile (coalesced global read) ----
    const size_t cbase = ((size_t)b * NPIX + n0) * C;
    for (int i = tid; i < NT * C; i += NT) {
        const int n = i / C;
        const int c = i - n * C;
        const float p  = cls_pred[cbase + i];
        const float q  = 1.0f - p;
        // pos = ALPHA * (1-p)^2 * (-log(p+EPS)); neg = (1-ALPHA) * p^2 * (-log(1-p+EPS))
        const float pos = (ALPHA_F * (q * q)) * (-logf(p + EPS_F));
        const float neg = ((1.0f - ALPHA_F) * (p * p)) * (-logf(q + EPS_F));
        D[c][n] = pos - neg;
    }

    // ---- stage targets ----
    for (int i = tid; i < M * 4; i += NT)
        lt[i >> 2][i & 3] = loc_true[(size_t)b * M * 4 + i];
    for (int i = tid; i < M; i += NT)
        lcid[i] = cids[b * M + i];

    // ---- per-thread cell box (loop-invariant over m) ----
    const int n = n0 + tid;
    const float inv = 1.0f / 128.0f;   // /[w,h,w,h], exact pow-2 scale
    const size_t lbase = ((size_t)b * NPIX + n) * 4;
    const float py1 = loc_pred[lbase + 0] * inv;
    const float px1 = loc_pred[lbase + 1] * inv;
    const float py2 = loc_pred[lbase + 2] * inv;
    const float px2 = loc_pred[lbase + 3] * inv;
    const float p_area = fmaxf(py2 - py1, 0.0f) * fmaxf(px2 - px1, 0.0f);

    __syncthreads();

    for (int m = 0; m < M; ++m) {
        const float ty1 = lt[m][0];
        const float tx1 = lt[m][1];
        const float ty2 = lt[m][2];
        const float tx2 = lt[m][3];
        const int   cid = lcid[m];

        const float d = D[cid][tid];

        // reg: sum(|loc_true - loc_p|), left-assoc like np
        const float r = ((fabsf(ty1 - py1) + fabsf(tx1 - px1))
                         + fabsf(ty2 - py2)) + fabsf(tx2 - px2);

        // giou
        const float t_area = fmaxf(ty2 - ty1, 0.0f) * fmaxf(tx2 - tx1, 0.0f);
        const float ih = fmaxf(fminf(py2, ty2) - fmaxf(py1, ty1), 0.0f);
        const float iw = fmaxf(fminf(px2, tx2) - fmaxf(px1, tx1), 0.0f);
        const float inter = ih * iw;
        const float uni   = (p_area + t_area) - inter;
        const float iou   = (uni > 0.0f) ? (inter / fmaxf(uni, EPS_F)) : 0.0f;
        const float eh = fmaxf(py2, ty2) - fminf(py1, ty1);
        const float ew = fmaxf(px2, tx2) - fminf(px1, tx1);
        const float enc = eh * ew;
        const float pen = (enc > 0.0f) ? ((enc - uni) / fmaxf(enc, EPS_F)) : 0.0f;
        const float gl  = 1.0f - (iou - pen);

        // total = 2*cls + 5*reg + 2*giou, left-assoc like np
        const float total = ((2.0f * d) + (5.0f * r)) + (2.0f * gl);

        // pack (cost, n): low bits = n => ties pick smallest n (argmin semantics)
        unsigned long long key =
            ((unsigned long long)fkey(total) << 32) | (unsigned int)n;

        // wave64 min-reduction
        #pragma unroll
        for (int off = 32; off > 0; off >>= 1) {
            unsigned long long o = __shfl_xor(key, off, 64);
            key = (o < key) ? o : key;
        }
        if ((tid & 63) == 0)
            atomicMin(&keys[b * M + m], key);
    }
}

// ---------------------------------------------------------------------------
// Kernel 3: unpack to (b, argmin, cid) int32
// ---------------------------------------------------------------------------
__global__ void write_out_kernel(const unsigned long long* __restrict__ keys,
                                 const int* __restrict__ cids,
                                 int* __restrict__ out) {
    int i = blockIdx.x * blockDim.x + threadIdx.x;
    if (i >= B * M) return;
    const int b = i / M;
    out[i * 3 + 0] = b;
    out[i * 3 + 1] = (int)(keys[i] & 0xFFFFFFFFull);
    out[i * 3 + 2] = cids[i];
}

extern "C" void kernel_launch(void* const* d_in, const int* in_sizes, int n_in,
                              void* d_out, int out_size, void* d_ws, size_t ws_size,
                              hipStream_t stream) {
    const float* cls_pred = (const float*)d_in[0];
    const float* loc_pred = (const float*)d_in[1];
    const float* cls_true = (const float*)d_in[2];
    const float* loc_true = (const float*)d_in[3];
    // d_in[4] = reg_mask (unused by the reference computation)

    unsigned long long* keys = (unsigned long long*)d_ws;
    int* cids = (int*)((char*)d_ws + (size_t)B * M * sizeof(unsigned long long));
    int* out = (int*)d_out;

    init_kernel<<<(B * M + 255) / 256, 256, 0, stream>>>(cls_true, keys, cids);

    dim3 grid(NPIX / NT, B);
    match_kernel<<<grid, NT, 0, stream>>>(cls_pred, loc_pred, loc_true, cids, keys);

    write_out_kernel<<<(B * M + 255) / 256, 256, 0, stream>>>(keys, cids, out);
}

// Round 2
// 78.712 us; speedup vs baseline: 2.9766x; 2.9766x over previous
//
#include <hip/hip_runtime.h>
#include <stdint.h>

// Problem dims (fixed by the reference's setup_inputs)
#define B    8
#define C    80
#define M    100
#define NPIX 16384          // 128*128

#define ALPHA_F 0.25f
#define EPS_F   1e-8f

// Order-preserving float -> uint32 map (total order; no NaNs expected here).
__device__ __forceinline__ uint32_t fkey(float f) {
    uint32_t u = __float_as_uint(f);
    return (u & 0x80000000u) ? ~u : (u | 0x80000000u);
}

// ---------------------------------------------------------------------------
// cids: per-(b,m) class id = argmax of one-hot row (first max index)
// ---------------------------------------------------------------------------
__global__ void cids_kernel(const float* __restrict__ cls_true,
                            int* __restrict__ cids) {
    int i = blockIdx.x * blockDim.x + threadIdx.x;
    if (i >= B * M) return;
    const float* ct = cls_true + (size_t)i * C;
    int best = 0;
    float bv = ct[0];
    for (int c = 1; c < C; ++c) {
        float v = ct[c];
        if (v > bv) { bv = v; best = c; }
    }
    cids[i] = best;
}

// ---------------------------------------------------------------------------
// transform+transpose: T[b][c][n] = pos - neg  (focal class cost)
// block = 256 threads, tile = 64 n x 80 c; coalesced read and write.
// ---------------------------------------------------------------------------
__global__ __launch_bounds__(256) void transform_kernel(
    const float* __restrict__ cls_pred,   // (B, NPIX, C)
    float* __restrict__ T)                // (B, C, NPIX)
{
#pragma clang fp contract(off)
    __shared__ float tile[C][65];         // [c][n], pad col for banks
    const int b   = blockIdx.y;
    const int n0  = blockIdx.x * 64;
    const int tid = threadIdx.x;

    const float* src = cls_pred + ((size_t)b * NPIX + n0) * C;
    #pragma unroll
    for (int k = 0; k < 20; ++k) {        // 64*80 = 5120 = 20*256
        const int idx = k * 256 + tid;
        const int n = idx / 80;
        const int c = idx - n * 80;
        const float p = src[idx];
        const float q = 1.0f - p;
        const float pos = (ALPHA_F * (q * q)) * (-logf(p + EPS_F));
        const float neg = ((1.0f - ALPHA_F) * (p * p)) * (-logf(q + EPS_F));
        tile[c][n] = pos - neg;
    }
    __syncthreads();

    float* dstb = T + (size_t)b * C * NPIX + n0;
    #pragma unroll
    for (int k = 0; k < 20; ++k) {
        const int idx = k * 256 + tid;
        const int c   = idx >> 6;         // 0..79
        const int col = idx & 63;
        dstb[(size_t)c * NPIX + col] = tile[c][col];
    }
}

// ---------------------------------------------------------------------------
// argmin: one block per (b,m); threads serially min over n; no atomics.
// ---------------------------------------------------------------------------
__global__ __launch_bounds__(256) void argmin_kernel(
    const float* __restrict__ T,          // (B, C, NPIX)
    const float* __restrict__ loc_pred,   // (B, NPIX, 4)
    const float* __restrict__ loc_true,   // (B, M, 4)
    const int*   __restrict__ cids,       // (B*M)
    int* __restrict__ out)                // (B*M, 3)
{
#pragma clang fp contract(off)
    const int bm  = blockIdx.x;           // 0..799
    const int b   = bm / M;
    const int tid = threadIdx.x;
    const int cid = cids[bm];

    const float ty1 = loc_true[bm * 4 + 0];
    const float tx1 = loc_true[bm * 4 + 1];
    const float ty2 = loc_true[bm * 4 + 2];
    const float tx2 = loc_true[bm * 4 + 3];
    const float t_area = fmaxf(ty2 - ty1, 0.0f) * fmaxf(tx2 - tx1, 0.0f);

    const float4* lp4  = (const float4*)(loc_pred + (size_t)b * NPIX * 4);
    const float4* trow = (const float4*)(T + ((size_t)b * C + cid) * NPIX);
    const float inv = 1.0f / 128.0f;

    unsigned long long best = 0xFFFFFFFFFFFFFFFFull;

    #pragma unroll 4
    for (int k = 0; k < 16; ++k) {
        const int i4 = tid + k * 256;     // float4 index into T row
        const float4 d4 = trow[i4];
        const float dd[4] = { d4.x, d4.y, d4.z, d4.w };
        const int nbase = i4 * 4;
        #pragma unroll
        for (int j = 0; j < 4; ++j) {
            const int n = nbase + j;
            const float4 lp = lp4[n];
            const float py1 = lp.x * inv;
            const float px1 = lp.y * inv;
            const float py2 = lp.z * inv;
            const float px2 = lp.w * inv;
            const float p_area = fmaxf(py2 - py1, 0.0f) * fmaxf(px2 - px1, 0.0f);

            const float d = dd[j];

            // reg: sum(|loc_true - loc_p|), left-assoc like np
            const float r = ((fabsf(ty1 - py1) + fabsf(tx1 - px1))
                             + fabsf(ty2 - py2)) + fabsf(tx2 - px2);

            // giou
            const float ih = fmaxf(fminf(py2, ty2) - fmaxf(py1, ty1), 0.0f);
            const float iw = fmaxf(fminf(px2, tx2) - fmaxf(px1, tx1), 0.0f);
            const float inter = ih * iw;
            const float uni   = (p_area + t_area) - inter;
            const float iou   = (uni > 0.0f) ? (inter / fmaxf(uni, EPS_F)) : 0.0f;
            const float eh = fmaxf(py2, ty2) - fminf(py1, ty1);
            const float ew = fmaxf(px2, tx2) - fminf(px1, tx1);
            const float enc = eh * ew;
            const float pen = (enc > 0.0f) ? ((enc - uni) / fmaxf(enc, EPS_F)) : 0.0f;
            const float gl  = 1.0f - (iou - pen);

            const float total = ((2.0f * d) + (5.0f * r)) + (2.0f * gl);

            const unsigned long long key =
                ((unsigned long long)fkey(total) << 32) | (unsigned int)n;
            if (key < best) best = key;
        }
    }

    // wave64 min-reduce, then cross-wave via LDS
    #pragma unroll
    for (int off = 32; off > 0; off >>= 1) {
        unsigned long long o = __shfl_xor(best, off, 64);
        if (o < best) best = o;
    }
    __shared__ unsigned long long red[4];
    if ((tid & 63) == 0) red[tid >> 6] = best;
    __syncthreads();
    if (tid == 0) {
        unsigned long long r = red[0];
        #pragma unroll
        for (int w = 1; w < 4; ++w) if (red[w] < r) r = red[w];
        out[bm * 3 + 0] = b;
        out[bm * 3 + 1] = (int)(r & 0xFFFFFFFFull);
        out[bm * 3 + 2] = cid;
    }
}

// ===========================================================================
// Fallback path (round-1 kernel, known-correct) for small ws_size
// ===========================================================================
__global__ void fb_init_kernel(const float* __restrict__ cls_true,
                               unsigned long long* __restrict__ keys,
                               int* __restrict__ cids) {
    int i = blockIdx.x * blockDim.x + threadIdx.x;
    if (i >= B * M) return;
    keys[i] = 0xFFFFFFFFFFFFFFFFull;
    const float* ct = cls_true + (size_t)i * C;
    int best = 0;
    float bv = ct[0];
    for (int c = 1; c < C; ++c) {
        float v = ct[c];
        if (v > bv) { bv = v; best = c; }
    }
    cids[i] = best;
}

#define NT 128
__global__ __launch_bounds__(NT) void fb_match_kernel(
    const float* __restrict__ cls_pred,
    const float* __restrict__ loc_pred,
    const float* __restrict__ loc_true,
    const int*   __restrict__ cids,
    unsigned long long* __restrict__ keys)
{
#pragma clang fp contract(off)
    __shared__ float D[C][NT + 1];
    __shared__ float lt[M][4];
    __shared__ int   lcid[M];

    const int b   = blockIdx.y;
    const int n0  = blockIdx.x * NT;
    const int tid = threadIdx.x;

    const size_t cbase = ((size_t)b * NPIX + n0) * C;
    for (int i = tid; i < NT * C; i += NT) {
        const int n = i / C;
        const int c = i - n * C;
        const float p  = cls_pred[cbase + i];
        const float q  = 1.0f - p;
        const float pos = (ALPHA_F * (q * q)) * (-logf(p + EPS_F));
        const float neg = ((1.0f - ALPHA_F) * (p * p)) * (-logf(q + EPS_F));
        D[c][n] = pos - neg;
    }
    for (int i = tid; i < M * 4; i += NT)
        lt[i >> 2][i & 3] = loc_true[(size_t)b * M * 4 + i];
    for (int i = tid; i < M; i += NT)
        lcid[i] = cids[b * M + i];

    const int n = n0 + tid;
    const float inv = 1.0f / 128.0f;
    const size_t lbase = ((size_t)b * NPIX + n) * 4;
    const float py1 = loc_pred[lbase + 0] * inv;
    const float px1 = loc_pred[lbase + 1] * inv;
    const float py2 = loc_pred[lbase + 2] * inv;
    const float px2 = loc_pred[lbase + 3] * inv;
    const float p_area = fmaxf(py2 - py1, 0.0f) * fmaxf(px2 - px1, 0.0f);

    __syncthreads();

    for (int m = 0; m < M; ++m) {
        const float ty1 = lt[m][0];
        const float tx1 = lt[m][1];
        const float ty2 = lt[m][2];
        const float tx2 = lt[m][3];
        const int   cid = lcid[m];
        const float d = D[cid][tid];
        const float r = ((fabsf(ty1 - py1) + fabsf(tx1 - px1))
                         + fabsf(ty2 - py2)) + fabsf(tx2 - px2);
        const float t_area = fmaxf(ty2 - ty1, 0.0f) * fmaxf(tx2 - tx1, 0.0f);
        const float ih = fmaxf(fminf(py2, ty2) - fmaxf(py1, ty1), 0.0f);
        const float iw = fmaxf(fminf(px2, tx2) - fmaxf(px1, tx1), 0.0f);
        const float inter = ih * iw;
        const float uni   = (p_area + t_area) - inter;
        const float iou   = (uni > 0.0f) ? (inter / fmaxf(uni, EPS_F)) : 0.0f;
        const float eh = fmaxf(py2, ty2) - fminf(py1, ty1);
        const float ew = fmaxf(px2, tx2) - fminf(px1, tx1);
        const float enc = eh * ew;
        const float pen = (enc > 0.0f) ? ((enc - uni) / fmaxf(enc, EPS_F)) : 0.0f;
        const float gl  = 1.0f - (iou - pen);
        const float total = ((2.0f * d) + (5.0f * r)) + (2.0f * gl);
        unsigned long long key =
            ((unsigned long long)fkey(total) << 32) | (unsigned int)n;
        #pragma unroll
        for (int off = 32; off > 0; off >>= 1) {
            unsigned long long o = __shfl_xor(key, off, 64);
            key = (o < key) ? o : key;
        }
        if ((tid & 63) == 0)
            atomicMin(&keys[b * M + m], key);
    }
}

__global__ void fb_write_out_kernel(const unsigned long long* __restrict__ keys,
                                    const int* __restrict__ cids,
                                    int* __restrict__ out) {
    int i = blockIdx.x * blockDim.x + threadIdx.x;
    if (i >= B * M) return;
    const int b = i / M;
    out[i * 3 + 0] = b;
    out[i * 3 + 1] = (int)(keys[i] & 0xFFFFFFFFull);
    out[i * 3 + 2] = cids[i];
}

// ===========================================================================
extern "C" void kernel_launch(void* const* d_in, const int* in_sizes, int n_in,
                              void* d_out, int out_size, void* d_ws, size_t ws_size,
                              hipStream_t stream) {
    const float* cls_pred = (const float*)d_in[0];
    const float* loc_pred = (const float*)d_in[1];
    const float* cls_true = (const float*)d_in[2];
    const float* loc_true = (const float*)d_in[3];
    int* out = (int*)d_out;

    const size_t t_bytes = (size_t)B * C * NPIX * sizeof(float);   // 41.9 MB
    const size_t need = t_bytes + (size_t)B * M * sizeof(int);

    if (ws_size >= need) {
        float* T   = (float*)d_ws;
        int* cids  = (int*)((char*)d_ws + t_bytes);

        cids_kernel<<<(B * M + 255) / 256, 256, 0, stream>>>(cls_true, cids);
        transform_kernel<<<dim3(NPIX / 64, B), 256, 0, stream>>>(cls_pred, T);
        argmin_kernel<<<B * M, 256, 0, stream>>>(T, loc_pred, loc_true, cids, out);
    } else {
        unsigned long long* keys = (unsigned long long*)d_ws;
        int* cids = (int*)((char*)d_ws + (size_t)B * M * sizeof(unsigned long long));
        fb_init_kernel<<<(B * M + 255) / 256, 256, 0, stream>>>(cls_true, keys, cids);
        dim3 grid(NPIX / NT, B);
        fb_match_kernel<<<grid, NT, 0, stream>>>(cls_pred, loc_pred, loc_true, cids, keys);
        fb_write_out_kernel<<<(B * M + 255) / 256, 256, 0, stream>>>(keys, cids, out);
    }
}

// Round 3
// 58.701 us; speedup vs baseline: 3.9914x; 1.3409x over previous
//
#include <hip/hip_runtime.h>
#include <stdint.h>

// Problem dims (fixed by the reference's setup_inputs)
#define B    8
#define C    80
#define M    100
#define NPIX 16384          // 128*128
#define SPLIT 8             // segment-blocks per (b,m)
#define NSEG (NPIX / SPLIT) // 2048 cells per block

#define ALPHA_F 0.25f
#define EPS_F   1e-8f

// Order-preserving float -> uint32 map (total order; no NaNs expected here).
__device__ __forceinline__ uint32_t fkey(float f) {
    uint32_t u = __float_as_uint(f);
    return (u & 0x80000000u) ? ~u : (u | 0x80000000u);
}

// ---------------------------------------------------------------------------
// init: per-(b,m) cid = argmax of one-hot row (first max index); key = +inf
// ---------------------------------------------------------------------------
__global__ void init_kernel(const float* __restrict__ cls_true,
                            int* __restrict__ cids,
                            unsigned long long* __restrict__ keys) {
    int i = blockIdx.x * blockDim.x + threadIdx.x;
    if (i >= B * M) return;
    keys[i] = 0xFFFFFFFFFFFFFFFFull;
    const float* ct = cls_true + (size_t)i * C;
    int best = 0;
    float bv = ct[0];
    for (int c = 1; c < C; ++c) {
        float v = ct[c];
        if (v > bv) { bv = v; best = c; }
    }
    cids[i] = best;
}

// ---------------------------------------------------------------------------
// transform+transpose: T[b][c][n] = pos - neg  (focal class cost)
// block = 256 threads, tile = 64 n x 80 c; coalesced read and write.
// ---------------------------------------------------------------------------
__global__ __launch_bounds__(256) void transform_kernel(
    const float* __restrict__ cls_pred,   // (B, NPIX, C)
    float* __restrict__ T)                // (B, C, NPIX)
{
#pragma clang fp contract(off)
    __shared__ float tile[C][65];         // [c][n], pad col for banks
    const int b   = blockIdx.y;
    const int n0  = blockIdx.x * 64;
    const int tid = threadIdx.x;

    const float* src = cls_pred + ((size_t)b * NPIX + n0) * C;
    #pragma unroll
    for (int k = 0; k < 20; ++k) {        // 64*80 = 5120 = 20*256
        const int idx = k * 256 + tid;
        const int n = idx / 80;
        const int c = idx - n * 80;
        const float p = src[idx];
        const float q = 1.0f - p;
        const float pos = (ALPHA_F * (q * q)) * (-logf(p + EPS_F));
        const float neg = ((1.0f - ALPHA_F) * (p * p)) * (-logf(q + EPS_F));
        tile[c][n] = pos - neg;
    }
    __syncthreads();

    float* dstb = T + (size_t)b * C * NPIX + n0;
    #pragma unroll
    for (int k = 0; k < 20; ++k) {
        const int idx = k * 256 + tid;
        const int c   = idx >> 6;         // 0..79
        const int col = idx & 63;
        dstb[(size_t)c * NPIX + col] = tile[c][col];
    }
}

// ---------------------------------------------------------------------------
// argmin (split): block = (segment, bm). Each thread min-scans 8 cells with a
// plain float compare (first-index ties via ascending n + strict <), packs a
// 64-bit (cost,n) key once, wave+LDS reduce, one atomicMin per block.
// ---------------------------------------------------------------------------
__global__ __launch_bounds__(256) void argmin_split_kernel(
    const float* __restrict__ T,          // (B, C, NPIX)
    const float* __restrict__ loc_pred,   // (B, NPIX, 4)
    const float* __restrict__ loc_true,   // (B, M, 4)
    const int*   __restrict__ cids,       // (B*M)
    unsigned long long* __restrict__ keys)// (B*M)
{
#pragma clang fp contract(off)
    const int bm  = blockIdx.y;           // 0..799
    const int b   = bm / M;
    const int seg = blockIdx.x;           // 0..SPLIT-1
    const int tid = threadIdx.x;
    const int cid = cids[bm];

    const float ty1 = loc_true[bm * 4 + 0];
    const float tx1 = loc_true[bm * 4 + 1];
    const float ty2 = loc_true[bm * 4 + 2];
    const float tx2 = loc_true[bm * 4 + 3];
    const float t_area = fmaxf(ty2 - ty1, 0.0f) * fmaxf(tx2 - tx1, 0.0f);

    const float4* lp4   = (const float4*)(loc_pred + (size_t)b * NPIX * 4);
    const float4* trow4 = (const float4*)(T + ((size_t)b * C + cid) * NPIX)
                          + seg * (NSEG / 4);
    const int n0 = seg * NSEG;
    const float inv = 1.0f / 128.0f;

    float bestv = __builtin_huge_valf();
    int   bestn = 0;

    #pragma unroll
    for (int k = 0; k < NSEG / 4 / 256; ++k) {   // 2 iters
        const int i4 = tid + k * 256;
        const float4 d4 = trow4[i4];
        const float dd[4] = { d4.x, d4.y, d4.z, d4.w };
        const int nbase = n0 + i4 * 4;
        #pragma unroll
        for (int j = 0; j < 4; ++j) {
            const int n = nbase + j;
            const float4 lp = lp4[n];
            const float py1 = lp.x * inv;
            const float px1 = lp.y * inv;
            const float py2 = lp.z * inv;
            const float px2 = lp.w * inv;
            const float p_area = fmaxf(py2 - py1, 0.0f) * fmaxf(px2 - px1, 0.0f);

            const float d = dd[j];

            // reg: sum(|loc_true - loc_p|), left-assoc like np
            const float r = ((fabsf(ty1 - py1) + fabsf(tx1 - px1))
                             + fabsf(ty2 - py2)) + fabsf(tx2 - px2);

            // giou
            const float ih = fmaxf(fminf(py2, ty2) - fmaxf(py1, ty1), 0.0f);
            const float iw = fmaxf(fminf(px2, tx2) - fmaxf(px1, tx1), 0.0f);
            const float inter = ih * iw;
            const float uni   = (p_area + t_area) - inter;
            const float iou   = (uni > 0.0f) ? (inter / fmaxf(uni, EPS_F)) : 0.0f;
            const float eh = fmaxf(py2, ty2) - fminf(py1, ty1);
            const float ew = fmaxf(px2, tx2) - fminf(px1, tx1);
            const float enc = eh * ew;
            const float pen = (enc > 0.0f) ? ((enc - uni) / fmaxf(enc, EPS_F)) : 0.0f;
            const float gl  = 1.0f - (iou - pen);

            const float total = ((2.0f * d) + (5.0f * r)) + (2.0f * gl);

            if (total < bestv) { bestv = total; bestn = n; }  // strict < => first index
        }
    }

    unsigned long long best =
        ((unsigned long long)fkey(bestv) << 32) | (unsigned int)bestn;

    // wave64 min-reduce, then cross-wave via LDS
    #pragma unroll
    for (int off = 32; off > 0; off >>= 1) {
        unsigned long long o = __shfl_xor(best, off, 64);
        if (o < best) best = o;
    }
    __shared__ unsigned long long red[4];
    if ((tid & 63) == 0) red[tid >> 6] = best;
    __syncthreads();
    if (tid == 0) {
        unsigned long long r = red[0];
        #pragma unroll
        for (int w = 1; w < 4; ++w) if (red[w] < r) r = red[w];
        atomicMin(&keys[bm], r);
    }
}

// ---------------------------------------------------------------------------
// writeout: unpack to (b, argmin, cid) int32
// ---------------------------------------------------------------------------
__global__ void write_out_kernel(const unsigned long long* __restrict__ keys,
                                 const int* __restrict__ cids,
                                 int* __restrict__ out) {
    int i = blockIdx.x * blockDim.x + threadIdx.x;
    if (i >= B * M) return;
    out[i * 3 + 0] = i / M;
    out[i * 3 + 1] = (int)(keys[i] & 0xFFFFFFFFull);
    out[i * 3 + 2] = cids[i];
}

// ===========================================================================
// Fallback path (round-1 kernel, known-correct) for small ws_size
// ===========================================================================
#define NT 128
__global__ __launch_bounds__(NT) void fb_match_kernel(
    const float* __restrict__ cls_pred,
    const float* __restrict__ loc_pred,
    const float* __restrict__ loc_true,
    const int*   __restrict__ cids,
    unsigned long long* __restrict__ keys)
{
#pragma clang fp contract(off)
    __shared__ float D[C][NT + 1];
    __shared__ float lt[M][4];
    __shared__ int   lcid[M];

    const int b   = blockIdx.y;
    const int n0  = blockIdx.x * NT;
    const int tid = threadIdx.x;

    const size_t cbase = ((size_t)b * NPIX + n0) * C;
    for (int i = tid; i < NT * C; i += NT) {
        const int n = i / C;
        const int c = i - n * C;
        const float p  = cls_pred[cbase + i];
        const float q  = 1.0f - p;
        const float pos = (ALPHA_F * (q * q)) * (-logf(p + EPS_F));
        const float neg = ((1.0f - ALPHA_F) * (p * p)) * (-logf(q + EPS_F));
        D[c][n] = pos - neg;
    }
    for (int i = tid; i < M * 4; i += NT)
        lt[i >> 2][i & 3] = loc_true[(size_t)b * M * 4 + i];
    for (int i = tid; i < M; i += NT)
        lcid[i] = cids[b * M + i];

    const int n = n0 + tid;
    const float inv = 1.0f / 128.0f;
    const size_t lbase = ((size_t)b * NPIX + n) * 4;
    const float py1 = loc_pred[lbase + 0] * inv;
    const float px1 = loc_pred[lbase + 1] * inv;
    const float py2 = loc_pred[lbase + 2] * inv;
    const float px2 = loc_pred[lbase + 3] * inv;
    const float p_area = fmaxf(py2 - py1, 0.0f) * fmaxf(px2 - px1, 0.0f);

    __syncthreads();

    for (int m = 0; m < M; ++m) {
        const float ty1 = lt[m][0];
        const float tx1 = lt[m][1];
        const float ty2 = lt[m][2];
        const float tx2 = lt[m][3];
        const int   cid = lcid[m];
        const float d = D[cid][tid];
        const float r = ((fabsf(ty1 - py1) + fabsf(tx1 - px1))
                         + fabsf(ty2 - py2)) + fabsf(tx2 - px2);
        const float t_area = fmaxf(ty2 - ty1, 0.0f) * fmaxf(tx2 - tx1, 0.0f);
        const float ih = fmaxf(fminf(py2, ty2) - fmaxf(py1, ty1), 0.0f);
        const float iw = fmaxf(fminf(px2, tx2) - fmaxf(px1, tx1), 0.0f);
        const float inter = ih * iw;
        const float uni   = (p_area + t_area) - inter;
        const float iou   = (uni > 0.0f) ? (inter / fmaxf(uni, EPS_F)) : 0.0f;
        const float eh = fmaxf(py2, ty2) - fminf(py1, ty1);
        const float ew = fmaxf(px2, tx2) - fminf(px1, tx1);
        const float enc = eh * ew;
        const float pen = (enc > 0.0f) ? ((enc - uni) / fmaxf(enc, EPS_F)) : 0.0f;
        const float gl  = 1.0f - (iou - pen);
        const float total = ((2.0f * d) + (5.0f * r)) + (2.0f * gl);
        unsigned long long key =
            ((unsigned long long)fkey(total) << 32) | (unsigned int)n;
        #pragma unroll
        for (int off = 32; off > 0; off >>= 1) {
            unsigned long long o = __shfl_xor(key, off, 64);
            key = (o < key) ? o : key;
        }
        if ((tid & 63) == 0)
            atomicMin(&keys[b * M + m], key);
    }
}

// ===========================================================================
extern "C" void kernel_launch(void* const* d_in, const int* in_sizes, int n_in,
                              void* d_out, int out_size, void* d_ws, size_t ws_size,
                              hipStream_t stream) {
    const float* cls_pred = (const float*)d_in[0];
    const float* loc_pred = (const float*)d_in[1];
    const float* cls_true = (const float*)d_in[2];
    const float* loc_true = (const float*)d_in[3];
    int* out = (int*)d_out;

    const size_t t_bytes = (size_t)B * C * NPIX * sizeof(float);   // 41.9 MB
    const size_t small   = (size_t)B * M * (sizeof(unsigned long long) + sizeof(int));

    if (ws_size >= t_bytes + small) {
        float* T = (float*)d_ws;
        unsigned long long* keys = (unsigned long long*)((char*)d_ws + t_bytes);
        int* cids = (int*)((char*)keys + (size_t)B * M * sizeof(unsigned long long));

        init_kernel<<<(B * M + 255) / 256, 256, 0, stream>>>(cls_true, cids, keys);
        transform_kernel<<<dim3(NPIX / 64, B), 256, 0, stream>>>(cls_pred, T);
        argmin_split_kernel<<<dim3(SPLIT, B * M), 256, 0, stream>>>(
            T, loc_pred, loc_true, cids, keys);
        write_out_kernel<<<(B * M + 255) / 256, 256, 0, stream>>>(keys, cids, out);
    } else {
        unsigned long long* keys = (unsigned long long*)d_ws;
        int* cids = (int*)((char*)d_ws + (size_t)B * M * sizeof(unsigned long long));
        init_kernel<<<(B * M + 255) / 256, 256, 0, stream>>>(cls_true, cids, keys);
        dim3 grid(NPIX / NT, B);
        fb_match_kernel<<<grid, NT, 0, stream>>>(cls_pred, loc_pred, loc_true, cids, keys);
        write_out_kernel<<<(B * M + 255) / 256, 256, 0, stream>>>(keys, cids, out);
    }
}